// Round 7
// baseline (893.821 us; speedup 1.0000x reference)
//
#include <hip/hip_runtime.h>
#include <stdint.h>

#define FP8_MAX 448.0f

typedef float f32x16 __attribute__((ext_vector_type(16)));
typedef int i32x8 __attribute__((ext_vector_type(8)));

// ---------- helpers ----------

// async global->LDS, 16B per lane. LDS dest must be wave-uniform base + lane*16.
__device__ __forceinline__ void async_load16(const void* gptr, void* lptr) {
  __builtin_amdgcn_global_load_lds(
      (const __attribute__((address_space(1))) unsigned int*)(uintptr_t)gptr,
      (__attribute__((address_space(3))) unsigned int*)(unsigned)(uintptr_t)lptr,
      16, 0, 0);
}

// pack 4 fp32 -> 4 fp8 e4m3fn bytes (RNE, OCP on gfx950), byte0 = a
__device__ __forceinline__ unsigned pack4_fp8(float a, float b, float c, float d) {
  int v = __builtin_amdgcn_cvt_pk_fp8_f32(a, b, 0, false);
  v = __builtin_amdgcn_cvt_pk_fp8_f32(c, d, v, true);
  return (unsigned)v;
}

__device__ __forceinline__ float clip_fp8(float q) {
  return fminf(FP8_MAX, fmaxf(-FP8_MAX, q));
}

// assemble a 32-byte A/B fragment from two 16B LDS chunks (o_hi = o_lo ^ 16)
__device__ __forceinline__ i32x8 frag32(const unsigned char* rowbase, int o_lo) {
  uint4 lo = *(const uint4*)(rowbase + o_lo);
  uint4 hi = *(const uint4*)(rowbase + (o_lo ^ 16));
  i32x8 f;
  f[0] = lo.x; f[1] = lo.y; f[2] = lo.z; f[3] = lo.w;
  f[4] = hi.x; f[5] = hi.y; f[6] = hi.z; f[7] = hi.w;
  return f;
}

// ---------- pass 1: amax reduction ----------

__global__ void k_amax(const float4* __restrict__ x, long n4, unsigned* __restrict__ out) {
  float m = 0.f;
  const long stride = (long)gridDim.x * blockDim.x;
  for (long i = (long)blockIdx.x * blockDim.x + threadIdx.x; i < n4; i += stride) {
    float4 v = x[i];
    m = fmaxf(m, fmaxf(fmaxf(fabsf(v.x), fabsf(v.y)), fmaxf(fabsf(v.z), fabsf(v.w))));
  }
#pragma unroll
  for (int off = 32; off > 0; off >>= 1)
    m = fmaxf(m, __shfl_xor(m, off, 64));
  __shared__ float sm[4];
  const int wv = threadIdx.x >> 6;
  if ((threadIdx.x & 63) == 0) sm[wv] = m;
  __syncthreads();
  if (threadIdx.x == 0) {
    m = fmaxf(fmaxf(sm[0], sm[1]), fmaxf(sm[2], sm[3]));
    // all values >= 0: uint bit-pattern order == float order
    atomicMax(out, __float_as_uint(m));
  }
}

// ---------- pass 2: quantize x. Unit-stride float4 loads, unit-stride u32 stores ----------

__global__ void k_quant_x(const float4* __restrict__ x, unsigned* __restrict__ q,
                          const unsigned* __restrict__ amax_bits) {
  const float scale = fmaxf(__uint_as_float(*amax_bits), 1e-12f) / 448.0f;
  const long i0 = (long)blockIdx.x * blockDim.x + threadIdx.x;
  const long stride = (long)gridDim.x * blockDim.x;
#pragma unroll
  for (int r = 0; r < 4; r++) {
    const long i = i0 + r * stride;
    float4 v = x[i];
    // true IEEE division to match reference rounding
    q[i] = pack4_fp8(clip_fp8(v.x / scale), clip_fp8(v.y / scale),
                     clip_fp8(v.z / scale), clip_fp8(v.w / scale));
  }
}

// ---------- pass 3: quantize weight (values pre-scaled; just clip+RNE->fp8) ----------

__global__ void k_quant_w(const float4* __restrict__ w, unsigned* __restrict__ q) {
  const long i0 = (long)blockIdx.x * blockDim.x + threadIdx.x;
  const long stride = (long)gridDim.x * blockDim.x;
#pragma unroll
  for (int r = 0; r < 4; r++) {
    const long i = i0 + r * stride;
    float4 v = w[i];
    q[i] = pack4_fp8(clip_fp8(v.x), clip_fp8(v.y), clip_fp8(v.z), clip_fp8(v.w));
  }
}

// ---------- pass 4: fp8 GEMM, 256x256 tile, BK=64, MODULO-SCHEDULED pipeline ----
//
// 8 waves (512 thr) as 2(M) x 4(N); wave tile 128x64 = acc[4][2] of 32x32.
// MFMA: mfma_scale_f32_32x32x64_f8f6f4, scales 0x7f (=2^0) -> plain fp8 GEMM.
//
// ROUND-7 CHANGE (from rounds 3+6 post-mortems): both prior schedules
// serialized the LDS pipe (~1150 cy/tile of ds_read_b128) against the MFMA
// pipe (~1100 cy/tile) because every MFMA of tile t waited on ds_reads issued
// IN tile t (3050-3430 cy/tile observed vs ~1300 overlap floor). Fix: rotate
// the loop (software pipeline) -- body t's 12 ds_reads fetch tile t+1's
// fragments while body t's 8 MFMAs consume registers read in body t-1. No
// MFMA depends on a same-body read, so the lgkm waits are for year-old reads
// (free) and the fresh reads execute in the LDS pipe UNDER the MFMAs in every
// wave. B-frags double-buffered in regs (+16 VGPR, static swap via 2x unroll);
// A-frags recycled in place (WAR, program order). ~244 regs < 256 @ 2 w/SIMD.
//
// Body t layout (sched_barrier(0) pins the 3 regions; raw s_barrier has no
// implied drain; compiler inserts fine-grained counted lgkm waits):
//   [4 MFMA(t): af0,af1 x bc]                     <- overlaps t's late reads
//   vmcnt(0) + barrier                            <- publish buf[(t+1)%3]
//   [issue 8 ds_reads(t+1): af0,af1,bn; stage(t+2) 4x global_load_lds]
//   [4 MFMA(t): af2,af3 x bc, interleaved with 4 ds_reads(t+1): af2,af3]
// vmcnt(0) at the publish point is counted-equivalent: the only outstanding
// loads are tile t+1's 4, issued a full body (~1100+ cy) earlier.
//
// Hazard audit: buf[(t+1)%3] published by vmcnt(0)+barrier before any read of
// it. stage(t+2) overwrites buf[(t-1)%3]; all waves' reads of tile t-1 data
// were issued in body t-2 and lgkm-consumed in body t-1, which precedes the
// body-t barrier that precedes the stage. One barrier per body; all guards
// block-uniform. NT must be even (K=4096 -> NT=64).
//
// Swizzle (64B rows, 4x16B chunks): slot = chunk ^ ((row>>1)&3), applied on
// the GLOBAL source during global_load_lds (LDS dest linear as HW requires)
// and on LDS offsets at read time.
//
// A-frag layout (32x32x64): m = lane&31, k = 32*(lane>>5) + byte_idx.
// C/D layout (32x32): col = lane&31, row = (reg&3) + 8*(reg>>2) + 4*(lane>>5).

#define MFMA_F8(d, a, b)                                                     \
  d = __builtin_amdgcn_mfma_scale_f32_32x32x64_f8f6f4(a, b, d, 0, 0, 0,      \
                                                      0x7f7f7f7f, 0, 0x7f7f7f7f)

// bc0/bc1: current-tile B frags (consumed); bn0/bn1: next-tile B frags (filled)
#define GEMM_BODY(T, bc0, bc1, bn0, bn1)                                     \
  {                                                                          \
    const bool hv1 = ((T) + 1 < NT);                                         \
    const bool hv2 = ((T) + 2 < NT);                                         \
    __builtin_amdgcn_s_setprio(1);                                           \
    MFMA_F8(acc[0][0], af0, bc0); MFMA_F8(acc[0][1], af0, bc1);              \
    MFMA_F8(acc[1][0], af1, bc0); MFMA_F8(acc[1][1], af1, bc1);              \
    __builtin_amdgcn_s_setprio(0);                                           \
    __builtin_amdgcn_sched_barrier(0);                                       \
    if (hv1) {                                                               \
      asm volatile("s_waitcnt vmcnt(0)" ::: "memory");                       \
      __builtin_amdgcn_s_barrier();                                          \
      const unsigned char* pa = lds + rA + a_rowoff;                         \
      const unsigned char* pb = lds + rB + b_rowoff;                         \
      af0 = frag32(pa, o_lo);                                                \
      af1 = frag32(pa + 2048, o_lo);                                         \
      bn0 = frag32(pb, o_lo);                                                \
      bn1 = frag32(pb + 2048, o_lo);                                         \
      if (hv2) {                                                             \
        const size_t kb = (size_t)((T) + 2) << 6;                            \
        async_load16(Ag + g_off[0] + kb, lds + sA + l_off[0]);               \
        async_load16(Ag + g_off[1] + kb, lds + sA + l_off[1]);               \
        async_load16(Bg + g_off[0] + kb, lds + sB + l_off[0]);               \
        async_load16(Bg + g_off[1] + kb, lds + sB + l_off[1]);               \
      }                                                                      \
    }                                                                        \
    __builtin_amdgcn_sched_barrier(0);                                       \
    __builtin_amdgcn_s_setprio(1);                                           \
    MFMA_F8(acc[2][0], af2, bc0); MFMA_F8(acc[2][1], af2, bc1);              \
    if (hv1) af2 = frag32(lds + rA + a_rowoff + 4096, o_lo);                 \
    MFMA_F8(acc[3][0], af3, bc0); MFMA_F8(acc[3][1], af3, bc1);              \
    if (hv1) af3 = frag32(lds + rA + a_rowoff + 6144, o_lo);                 \
    __builtin_amdgcn_s_setprio(0);                                           \
    { int tmp = fA; fA = rA; rA = sA; sA = tmp; }                            \
    { int tmp = fB; fB = rB; rB = sB; sB = tmp; }                            \
  }

__global__ __launch_bounds__(512, 2) void k_gemm(
    const unsigned char* __restrict__ qa, const unsigned char* __restrict__ qb,
    const unsigned* __restrict__ amax_bits, const float* __restrict__ wscale,
    const float* __restrict__ bias, float* __restrict__ out,
    int M, int N, int K) {
  __shared__ unsigned char lds[98304];

  const int t = threadIdx.x;
  const int lane = t & 63;
  const int wv = t >> 6;        // 0..7
  const int wm = wv >> 2;       // 0..1  (M dir)
  const int wn = wv & 3;        // 0..3  (N dir)
  const int lr = lane & 31;
  const int h = lane >> 5;      // K-half selector
  const int key = (lr >> 1) & 3;

  // plain 2D grid: bx (n) fastest -> round-robin over XCDs keeps 2 B-panels
  // per XCD L2-resident; L3 absorbs cross-XCD A re-reads.
  const int bx = blockIdx.x;    // n tile (256 wide)
  const int by = blockIdx.y;    // m tile (256 tall)

  const unsigned char* Ag = qa + (size_t)by * 256 * K;
  const unsigned char* Bg = qb + (size_t)bx * 256 * K;

  // staging: one tile = 16KB = 1024 chunks; 512 thr x 2. idx -> row=idx>>2,
  // chunk slot cs=idx&3 holds global chunk cs^((row>>1)&3).
  size_t g_off[2]; int l_off[2];
#pragma unroll
  for (int r = 0; r < 2; r++) {
    const int idx = t + r * 512;
    const int row = idx >> 2;
    const int cs = idx & 3;
    g_off[r] = (size_t)row * K + (size_t)((cs ^ ((row >> 1) & 3)) << 4);
    l_off[r] = idx << 4;
  }

  // fragment read: lane's 32B = chunks {2h, 2h+1} of its row, at swizzled slots
  const int o_lo = ((2 * h) ^ key) << 4;  // partner chunk at o_lo ^ 16
  const int a_rowoff = (wm * 128 + lr) * 64;  // + im*2048 per m-subtile
  const int b_rowoff = (wn * 64 + lr) * 64;   // + nj*2048 per n-subtile

  f32x16 acc[4][2];
#pragma unroll
  for (int i = 0; i < 4; i++)
#pragma unroll
    for (int j = 0; j < 2; j++)
#pragma unroll
      for (int r = 0; r < 16; r++) acc[i][j][r] = 0.f;

  // buffer bases: fA/fB hold tile 0 (read in prologue), rA/rB hold tile 1
  // (read in body 0), sA/sB are the stage target for tile 2 (body 0).
  int fA = 0, rA = 16384, sA = 32768;
  int fB = 49152, rB = 65536, sB = 81920;

  // ---- prologue: stage tiles 0 and 1, read all 12 frags of tile 0 ----
#pragma unroll
  for (int r = 0; r < 2; r++) {
    async_load16(Ag + g_off[r], lds + fA + l_off[r]);
    async_load16(Bg + g_off[r], lds + fB + l_off[r]);
  }
#pragma unroll
  for (int r = 0; r < 2; r++) {
    async_load16(Ag + g_off[r] + 64, lds + rA + l_off[r]);
    async_load16(Bg + g_off[r] + 64, lds + rB + l_off[r]);
  }
  asm volatile("s_waitcnt vmcnt(4)" ::: "memory");  // tile 0 landed; tile 1 in flight
  __builtin_amdgcn_s_barrier();

  i32x8 af0, af1, af2, af3, bfA0, bfA1, bfB0, bfB1;
  {
    const unsigned char* pa = lds + fA + a_rowoff;
    const unsigned char* pb = lds + fB + b_rowoff;
    af0 = frag32(pa, o_lo);
    af1 = frag32(pa + 2048, o_lo);
    af2 = frag32(pa + 4096, o_lo);
    af3 = frag32(pa + 6144, o_lo);
    bfA0 = frag32(pb, o_lo);
    bfA1 = frag32(pb + 2048, o_lo);
  }

  const int NT = K >> 6;  // even for K % 128 == 0 (problem: K=4096 -> 64)
  for (int tt = 0; tt < NT; tt += 2) {
    GEMM_BODY(tt, bfA0, bfA1, bfB0, bfB1);
    GEMM_BODY(tt + 1, bfB0, bfB1, bfA0, bfA1);
  }

  // ---- epilogue ----
  const float s_comb =
      (fmaxf(__uint_as_float(*amax_bits), 1e-12f) / 448.0f) * wscale[0];
#pragma unroll
  for (int nj = 0; nj < 2; ++nj) {
    const int col = bx * 256 + wn * 64 + nj * 32 + lr;
    const float bv = bias[col];
#pragma unroll
    for (int mi = 0; mi < 4; ++mi) {
      const int row0 = by * 256 + wm * 128 + mi * 32 + 4 * h;
#pragma unroll
      for (int r = 0; r < 16; ++r) {
        const int row = row0 + (r & 3) + 8 * (r >> 2);
        out[(size_t)row * N + col] = acc[mi][nj][r] * s_comb + bv;
      }
    }
  }
}

// ---------- launch ----------

extern "C" void kernel_launch(void* const* d_in, const int* in_sizes, int n_in,
                              void* d_out, int out_size, void* d_ws, size_t ws_size,
                              hipStream_t stream) {
  const float* x = (const float*)d_in[0];        // [B,S,K] fp32
  const float* qw = (const float*)d_in[1];       // [N,K] fp32 (pre-scaled fp8 values)
  const float* wscale = (const float*)d_in[2];   // [1] fp32
  const float* bias = (const float*)d_in[3];     // [N] fp32

  const int N = in_sizes[3];
  const int K = in_sizes[1] / N;
  const int M = in_sizes[0] / K;

  const long nx = (long)M * K;
  const long nw = (long)N * K;

  unsigned char* ws = (unsigned char*)d_ws;
  unsigned* amax_bits = (unsigned*)ws;
  unsigned char* qx8 = ws + 256;
  unsigned char* qw8 = qx8 + nx;

  float* out = (float*)d_out;

  hipMemsetAsync(d_ws, 0, 4, stream);
  k_amax<<<2048, 256, 0, stream>>>((const float4*)x, nx / 4, amax_bits);
  // each thread handles 4 float4s, unit-stride within each pass
  k_quant_x<<<(int)(nx / 4 / 4 / 256), 256, 0, stream>>>(
      (const float4*)x, (unsigned*)qx8, amax_bits);
  k_quant_w<<<(int)(nw / 4 / 4 / 256), 256, 0, stream>>>(
      (const float4*)qw, (unsigned*)qw8);
  dim3 grid(N / 256, M / 256);
  k_gemm<<<grid, 512, 0, stream>>>(qx8, qw8, amax_bits, wscale, bias, out,
                                   M, N, K);
}

// Round 8
// 426.295 us; speedup vs baseline: 2.0967x; 2.0967x over previous
//
#include <hip/hip_runtime.h>
#include <stdint.h>

#define FP8_MAX 448.0f

typedef float f32x16 __attribute__((ext_vector_type(16)));
typedef int i32x8 __attribute__((ext_vector_type(8)));

// ---------- helpers ----------

// async global->LDS, 16B per lane. LDS dest must be wave-uniform base + lane*16.
__device__ __forceinline__ void async_load16(const void* gptr, void* lptr) {
  __builtin_amdgcn_global_load_lds(
      (const __attribute__((address_space(1))) unsigned int*)(uintptr_t)gptr,
      (__attribute__((address_space(3))) unsigned int*)(unsigned)(uintptr_t)lptr,
      16, 0, 0);
}

// pack 4 fp32 -> 4 fp8 e4m3fn bytes (RNE, OCP on gfx950), byte0 = a
__device__ __forceinline__ unsigned pack4_fp8(float a, float b, float c, float d) {
  int v = __builtin_amdgcn_cvt_pk_fp8_f32(a, b, 0, false);
  v = __builtin_amdgcn_cvt_pk_fp8_f32(c, d, v, true);
  return (unsigned)v;
}

__device__ __forceinline__ float clip_fp8(float q) {
  return fminf(FP8_MAX, fmaxf(-FP8_MAX, q));
}

// assemble a 32-byte A/B fragment from two 16B LDS chunks (o_hi = o_lo ^ 16)
__device__ __forceinline__ i32x8 frag32(const unsigned char* rowbase, int o_lo) {
  uint4 lo = *(const uint4*)(rowbase + o_lo);
  uint4 hi = *(const uint4*)(rowbase + (o_lo ^ 16));
  i32x8 f;
  f[0] = lo.x; f[1] = lo.y; f[2] = lo.z; f[3] = lo.w;
  f[4] = hi.x; f[5] = hi.y; f[6] = hi.z; f[7] = hi.w;
  return f;
}

// ---------- pass 1: amax(x) reduction FUSED with quant_w (independent work) ----
// Blocks [0, nb_amax) run the amax reduction over x (identical code/order to
// the proven k_amax). Blocks [nb_amax, grid) quantize the weight (identical
// code to the proven k_quant_w). quant_w has no dependency on amax, so fusing
// removes one serial graph node and hides quant_w's time under the amax pass.

__global__ void k_amax_qw(const float4* __restrict__ x, long n4x,
                          const float4* __restrict__ w, unsigned* __restrict__ qw,
                          unsigned* __restrict__ amax_bits, int nb_amax) {
  if ((int)blockIdx.x < nb_amax) {
    // ---- amax role ----
    float m = 0.f;
    const long stride = (long)nb_amax * blockDim.x;
    for (long i = (long)blockIdx.x * blockDim.x + threadIdx.x; i < n4x; i += stride) {
      float4 v = x[i];
      m = fmaxf(m, fmaxf(fmaxf(fabsf(v.x), fabsf(v.y)), fmaxf(fabsf(v.z), fabsf(v.w))));
    }
#pragma unroll
    for (int off = 32; off > 0; off >>= 1)
      m = fmaxf(m, __shfl_xor(m, off, 64));
    __shared__ float sm[4];
    const int wv = threadIdx.x >> 6;
    if ((threadIdx.x & 63) == 0) sm[wv] = m;
    __syncthreads();
    if (threadIdx.x == 0) {
      m = fmaxf(fmaxf(sm[0], sm[1]), fmaxf(sm[2], sm[3]));
      // all values >= 0: uint bit-pattern order == float order
      atomicMax(amax_bits, __float_as_uint(m));
    }
  } else {
    // ---- quant_w role (values pre-scaled; clip+RNE->fp8) ----
    const int b = (int)blockIdx.x - nb_amax;
    const int nbw = (int)gridDim.x - nb_amax;
    const long i0 = (long)b * blockDim.x + threadIdx.x;
    const long stride = (long)nbw * blockDim.x;
#pragma unroll
    for (int r = 0; r < 4; r++) {
      const long i = i0 + r * stride;
      float4 v = w[i];
      qw[i] = pack4_fp8(clip_fp8(v.x), clip_fp8(v.y), clip_fp8(v.z), clip_fp8(v.w));
    }
  }
}

// ---------- pass 2: quantize x. Unit-stride float4 loads, unit-stride u32 stores ----------

__global__ void k_quant_x(const float4* __restrict__ x, unsigned* __restrict__ q,
                          const unsigned* __restrict__ amax_bits) {
  const float scale = fmaxf(__uint_as_float(*amax_bits), 1e-12f) / 448.0f;
  const long i0 = (long)blockIdx.x * blockDim.x + threadIdx.x;
  const long stride = (long)gridDim.x * blockDim.x;
#pragma unroll
  for (int r = 0; r < 4; r++) {
    const long i = i0 + r * stride;
    float4 v = x[i];
    // true IEEE division to match reference rounding
    q[i] = pack4_fp8(clip_fp8(v.x / scale), clip_fp8(v.y / scale),
                     clip_fp8(v.z / scale), clip_fp8(v.w / scale));
  }
}

// ---------- pass 3: fp8 GEMM, 256x256 tile, BK=64, triple-buffered counted pipeline ----
// (byte-identical to the round-3 version that measured 163 us / MfmaUtil 36%)
//
// 8 waves (512 thr) as 2(M) x 4(N); wave tile 128x64 = acc[4][2] of 32x32.
// MFMA: mfma_scale_f32_32x32x64_f8f6f4, scales 0x7f (=2^0) -> plain fp8 GEMM at
// 2x the non-scaled rate.
//
// LDS 96 KiB: A[3 bufs x 16KB] @0, B[3 bufs x 16KB] @49152. TRIPLE buffer:
// tile t reads buf[t%3]; loads for t+2 issue during tile t. Boundary wait is a
// COUNTED s_waitcnt vmcnt(4): keep the 4 newest loads (tile t+2's) in flight,
// wait only for tile t+1's, issued a full tile ago -> HBM latency amortized.
//
// REGISTER BUDGET NOTE (round-7 lesson): unified VGPR+AGPR cap at
// __launch_bounds__(512,2) is 256/lane. acc = 128 AGPR; this schedule's
// ~100 VGPR fits (228 total). Deeper reg-pipelining (8 live frags) needed
// ~290 -> spilled to scratch (WRITE_SIZE 131MB -> 1.5GB, MfmaUtil 9%).
//
// Swizzle (64B rows, 4x16B chunks): slot = chunk ^ ((row>>1)&3), applied on
// the GLOBAL source during global_load_lds (LDS dest linear as HW requires)
// and on LDS offsets at read time.
//
// A-frag layout (32x32x64): m = lane&31, k = 32*(lane>>5) + byte_idx.
// C/D layout (32x32): col = lane&31, row = (reg&3) + 8*(reg>>2) + 4*(lane>>5).

__global__ __launch_bounds__(512, 2) void k_gemm(
    const unsigned char* __restrict__ qa, const unsigned char* __restrict__ qb,
    const unsigned* __restrict__ amax_bits, const float* __restrict__ wscale,
    const float* __restrict__ bias, float* __restrict__ out,
    int M, int N, int K) {
  __shared__ unsigned char lds[98304];

  const int t = threadIdx.x;
  const int lane = t & 63;
  const int wv = t >> 6;        // 0..7
  const int wm = wv >> 2;       // 0..1  (M dir)
  const int wn = wv & 3;        // 0..3  (N dir)
  const int lr = lane & 31;
  const int h = lane >> 5;      // K-half selector
  const int key = (lr >> 1) & 3;

  // plain 2D grid: bx (n) fastest -> round-robin over XCDs keeps 2 B-panels
  // per XCD L2-resident; L3 absorbs cross-XCD A re-reads.
  const int bx = blockIdx.x;    // n tile (256 wide)
  const int by = blockIdx.y;    // m tile (256 tall)

  const unsigned char* Ag = qa + (size_t)by * 256 * K;
  const unsigned char* Bg = qb + (size_t)bx * 256 * K;

  // staging: one tile = 16KB = 1024 chunks; 512 thr x 2. idx -> row=idx>>2,
  // chunk slot cs=idx&3 holds global chunk cs^((row>>1)&3).
  size_t g_off[2]; int l_off[2];
#pragma unroll
  for (int r = 0; r < 2; r++) {
    const int idx = t + r * 512;
    const int row = idx >> 2;
    const int cs = idx & 3;
    g_off[r] = (size_t)row * K + (size_t)((cs ^ ((row >> 1) & 3)) << 4);
    l_off[r] = idx << 4;
  }

  // fragment read: lane's 32B = chunks {2h, 2h+1} of its row, at swizzled slots
  const int o_lo = ((2 * h) ^ key) << 4;  // partner chunk at o_lo ^ 16
  const int a_rowoff = (wm * 128 + lr) * 64;  // + im*2048 per m-subtile
  const int b_rowoff = (wn * 64 + lr) * 64;   // + nj*2048 per n-subtile

  f32x16 acc[4][2];
#pragma unroll
  for (int i = 0; i < 4; i++)
#pragma unroll
    for (int j = 0; j < 2; j++)
#pragma unroll
      for (int r = 0; r < 16; r++) acc[i][j][r] = 0.f;

  // rotating buffer bases: read a0/b0, prefetch into a2/b2
  int a0 = 0, a1 = 16384, a2 = 32768;
  int b0 = 49152, b1 = 65536, b2 = 81920;

  // ---- prologue: stage tiles 0 and 1 ----
#pragma unroll
  for (int r = 0; r < 2; r++) {
    async_load16(Ag + g_off[r], lds + a0 + l_off[r]);
    async_load16(Bg + g_off[r], lds + b0 + l_off[r]);
  }
#pragma unroll
  for (int r = 0; r < 2; r++) {
    async_load16(Ag + g_off[r] + 64, lds + a1 + l_off[r]);
    async_load16(Bg + g_off[r] + 64, lds + b1 + l_off[r]);
  }
  asm volatile("s_waitcnt vmcnt(4)" ::: "memory");  // tile 0 landed; tile 1 in flight
  __builtin_amdgcn_s_barrier();

  const int NT = K >> 6;
  for (int tile = 0; tile < NT; ++tile) {
    const bool haveS = (tile + 2 < NT);
    const size_t kb2 = (size_t)(tile + 2) << 6;
    const unsigned char* pa = lds + a0 + a_rowoff;
    const unsigned char* pb = lds + b0 + b_rowoff;

    // ---- phase 0: af[0..1], bf[0..1]; stage A(t+2); 4 MFMA ----
    i32x8 af0 = frag32(pa, o_lo);
    i32x8 af1 = frag32(pa + 2048, o_lo);
    i32x8 bf0 = frag32(pb, o_lo);
    i32x8 bf1 = frag32(pb + 2048, o_lo);
    if (haveS) {
#pragma unroll
      for (int r = 0; r < 2; r++)
        async_load16(Ag + g_off[r] + kb2, lds + a2 + l_off[r]);
    }
    __builtin_amdgcn_s_barrier();
    asm volatile("s_waitcnt lgkmcnt(0)" ::: "memory");
    __builtin_amdgcn_sched_barrier(0);
    __builtin_amdgcn_s_setprio(1);
    acc[0][0] = __builtin_amdgcn_mfma_scale_f32_32x32x64_f8f6f4(
        af0, bf0, acc[0][0], 0, 0, 0, 0x7f7f7f7f, 0, 0x7f7f7f7f);
    acc[0][1] = __builtin_amdgcn_mfma_scale_f32_32x32x64_f8f6f4(
        af0, bf1, acc[0][1], 0, 0, 0, 0x7f7f7f7f, 0, 0x7f7f7f7f);
    acc[1][0] = __builtin_amdgcn_mfma_scale_f32_32x32x64_f8f6f4(
        af1, bf0, acc[1][0], 0, 0, 0, 0x7f7f7f7f, 0, 0x7f7f7f7f);
    acc[1][1] = __builtin_amdgcn_mfma_scale_f32_32x32x64_f8f6f4(
        af1, bf1, acc[1][1], 0, 0, 0, 0x7f7f7f7f, 0, 0x7f7f7f7f);
    __builtin_amdgcn_s_setprio(0);
    __builtin_amdgcn_sched_barrier(0);
    __builtin_amdgcn_s_barrier();

    // ---- phase 1: af[2..3] (bf persists); stage B(t+2); 4 MFMA ----
    i32x8 af2 = frag32(pa + 4096, o_lo);
    i32x8 af3 = frag32(pa + 6144, o_lo);
    if (haveS) {
#pragma unroll
      for (int r = 0; r < 2; r++)
        async_load16(Bg + g_off[r] + kb2, lds + b2 + l_off[r]);
    }
    __builtin_amdgcn_s_barrier();
    asm volatile("s_waitcnt lgkmcnt(0)" ::: "memory");
    __builtin_amdgcn_sched_barrier(0);
    __builtin_amdgcn_s_setprio(1);
    acc[2][0] = __builtin_amdgcn_mfma_scale_f32_32x32x64_f8f6f4(
        af2, bf0, acc[2][0], 0, 0, 0, 0x7f7f7f7f, 0, 0x7f7f7f7f);
    acc[2][1] = __builtin_amdgcn_mfma_scale_f32_32x32x64_f8f6f4(
        af2, bf1, acc[2][1], 0, 0, 0, 0x7f7f7f7f, 0, 0x7f7f7f7f);
    acc[3][0] = __builtin_amdgcn_mfma_scale_f32_32x32x64_f8f6f4(
        af3, bf0, acc[3][0], 0, 0, 0, 0x7f7f7f7f, 0, 0x7f7f7f7f);
    acc[3][1] = __builtin_amdgcn_mfma_scale_f32_32x32x64_f8f6f4(
        af3, bf1, acc[3][1], 0, 0, 0, 0x7f7f7f7f, 0, 0x7f7f7f7f);
    __builtin_amdgcn_s_setprio(0);
    __builtin_amdgcn_sched_barrier(0);

    // ---- boundary: counted wait (tile t+1's loads landed; t+2's may fly) ----
    if (haveS) {
      asm volatile("s_waitcnt vmcnt(4)" ::: "memory");
    } else {
      asm volatile("s_waitcnt vmcnt(0)" ::: "memory");
    }
    __builtin_amdgcn_s_barrier();

    // rotate buffers
    int ta = a0; a0 = a1; a1 = a2; a2 = ta;
    int tb = b0; b0 = b1; b1 = b2; b2 = tb;
  }

  // ---- epilogue ----
  const float s_comb =
      (fmaxf(__uint_as_float(*amax_bits), 1e-12f) / 448.0f) * wscale[0];
#pragma unroll
  for (int nj = 0; nj < 2; ++nj) {
    const int col = bx * 256 + wn * 64 + nj * 32 + lr;
    const float bv = bias[col];
#pragma unroll
    for (int mi = 0; mi < 4; ++mi) {
      const int row0 = by * 256 + wm * 128 + mi * 32 + 4 * h;
#pragma unroll
      for (int r = 0; r < 16; ++r) {
        const int row = row0 + (r & 3) + 8 * (r >> 2);
        out[(size_t)row * N + col] = acc[mi][nj][r] * s_comb + bv;
      }
    }
  }
}

// ---------- launch ----------

extern "C" void kernel_launch(void* const* d_in, const int* in_sizes, int n_in,
                              void* d_out, int out_size, void* d_ws, size_t ws_size,
                              hipStream_t stream) {
  const float* x = (const float*)d_in[0];        // [B,S,K] fp32
  const float* qw = (const float*)d_in[1];       // [N,K] fp32 (pre-scaled fp8 values)
  const float* wscale = (const float*)d_in[2];   // [1] fp32
  const float* bias = (const float*)d_in[3];     // [N] fp32

  const int N = in_sizes[3];
  const int K = in_sizes[1] / N;
  const int M = in_sizes[0] / K;

  const long nx = (long)M * K;
  const long nw = (long)N * K;

  unsigned char* ws = (unsigned char*)d_ws;
  unsigned* amax_bits = (unsigned*)ws;
  unsigned char* qx8 = ws + 256;
  unsigned char* qw8 = qx8 + nx;

  float* out = (float*)d_out;

  hipMemsetAsync(d_ws, 0, 4, stream);

  // fused: amax(x) [2048 blocks] || quant_w [nw/4/4/256 blocks]
  const int nb_amax = 2048;
  const int nb_qw = (int)(nw / 4 / 4 / 256);
  k_amax_qw<<<nb_amax + nb_qw, 256, 0, stream>>>(
      (const float4*)x, nx / 4, (const float4*)qw, (unsigned*)qw8,
      amax_bits, nb_amax);

  // quantize x (depends on amax)
  k_quant_x<<<(int)(nx / 4 / 4 / 256), 256, 0, stream>>>(
      (const float4*)x, (unsigned*)qx8, amax_bits);

  dim3 grid(N / 256, M / 256);
  k_gemm<<<grid, 512, 0, stream>>>(qx8, qw8, amax_bits, wscale, bias, out,
                                   M, N, K);
}